// Round 1
// baseline (1999.982 us; speedup 1.0000x reference)
//
#include <hip/hip_runtime.h>
#include <stdint.h>

#define T_TOK 32768
#define DIM   1024
#define NEXP  8
#define DFFN  2048
#define MAXROWS 66560   // 65536 + 8*128 padding capacity, multiple of 128
#define BM 128

typedef __bf16 bf16x8 __attribute__((ext_vector_type(8)));
typedef float  f32x4  __attribute__((ext_vector_type(4)));

__device__ __forceinline__ unsigned short f2bf(float f) {
  unsigned u = __float_as_uint(f);
  unsigned r = (u + 0x7fffu + ((u >> 16) & 1u)) >> 16;
  return (unsigned short)r;
}

__device__ __forceinline__ void gload16(const void* g, void* l) {
  __builtin_amdgcn_global_load_lds(
      (__attribute__((address_space(1))) void*)(uintptr_t)g,
      (__attribute__((address_space(3))) void*)(uint32_t)(uintptr_t)l,
      16, 0, 0);
}

// ---------------- routing ----------------
__global__ void route_kernel(const float* __restrict__ gating, int* __restrict__ sel,
                             float* __restrict__ selw, int* __restrict__ counts) {
  int t = blockIdx.x * 256 + threadIdx.x;
  if (t >= T_TOK) return;
  float4 a = ((const float4*)gating)[t * 2];
  float4 b = ((const float4*)gating)[t * 2 + 1];
  float l[8] = {a.x, a.y, a.z, a.w, b.x, b.y, b.z, b.w};
  int i0 = 0; float b0 = l[0];
#pragma unroll
  for (int i = 1; i < 8; ++i) if (l[i] > b0) { b0 = l[i]; i0 = i; }
  int i1 = -1; float b1 = -1e30f;
#pragma unroll
  for (int i = 0; i < 8; ++i) if (i != i0 && l[i] > b1) { b1 = l[i]; i1 = i; }
  // renormalized top-2 softmax == 2-way softmax of top-2 logits
  float e1 = __expf(b1 - b0);
  float w0 = 1.f / (1.f + e1);
  float w1 = 1.f - w0;
  sel[2 * t] = i0;  sel[2 * t + 1] = i1;
  selw[2 * t] = w0; selw[2 * t + 1] = w1;
  atomicAdd(&counts[i0], 1);
  atomicAdd(&counts[i1], 1);
}

__global__ void offsets_kernel(const int* __restrict__ counts, int* __restrict__ padOff) {
  if (threadIdx.x == 0) {
    int off = 0;
    for (int e = 0; e < NEXP; ++e) { padOff[e] = off; off += (counts[e] + 127) & ~127; }
    padOff[NEXP] = off;
  }
}

__global__ void fill_kernel(int* __restrict__ rowTok, float* __restrict__ rowWgt) {
  int i = blockIdx.x * 256 + threadIdx.x;
  if (i < MAXROWS) { rowTok[i] = 0; rowWgt[i] = 0.f; }
}

__global__ void scatter_kernel(const int* __restrict__ sel, const float* __restrict__ selw,
                               const int* __restrict__ padOff, int* __restrict__ cursors,
                               int* __restrict__ rowTok, float* __restrict__ rowWgt) {
  int t = blockIdx.x * 256 + threadIdx.x;
  if (t >= T_TOK) return;
#pragma unroll
  for (int j = 0; j < 2; ++j) {
    int e = sel[2 * t + j];
    int pos = atomicAdd(&cursors[e], 1);
    int r = padOff[e] + pos;
    rowTok[r] = t;
    rowWgt[r] = selw[2 * t + j];
  }
}

// ---------------- f32 -> bf16 conversion ----------------
__global__ void cvt_kernel(const float* __restrict__ src, unsigned short* __restrict__ dst, int n4) {
  int i = blockIdx.x * blockDim.x + threadIdx.x;
  int stride = gridDim.x * blockDim.x;
  for (; i < n4; i += stride) {
    float4 v = ((const float4*)src)[i];
    ushort4 o;
    o.x = f2bf(v.x); o.y = f2bf(v.y); o.z = f2bf(v.z); o.w = f2bf(v.w);
    ((ushort4*)dst)[i] = o;
  }
}

// ---------------- grouped GEMM1: gu = x @ w13[e]^T, H = silu(g)*u ----------------
// tile: 128 rows x 64 f-cols (both gate and up halves), BK=32, 4 waves
__global__ __launch_bounds__(256) void gemm1_kernel(
    const unsigned short* __restrict__ xbf, const unsigned short* __restrict__ w13bf,
    const int* __restrict__ rowTok, const int* __restrict__ padOff,
    unsigned short* __restrict__ H) {
  __shared__ __align__(16) unsigned short As[BM][32];
  __shared__ __align__(16) unsigned short Bs[BM][32];

  const int m0 = blockIdx.y * BM;
  const int total = padOff[NEXP];
  if (m0 >= total) return;
  int e = 0;
#pragma unroll
  for (int i = 1; i < NEXP; ++i) if (m0 >= padOff[i]) e = i;
  const int n0 = blockIdx.x * 64;  // f-column block

  const int tid = threadIdx.x;
  const int wv = tid >> 6, ln = tid & 63;
  const int wr = wv >> 1, wc = wv & 1;

  // staging: chunk c = wv*64+ln (issue0), 256+wv*64+ln (issue1); row=c>>2, slot=c&3
  const int rA0 = wv * 16 + (ln >> 2);
  const int rA1 = 64 + rA0;
  const int sl = (ln & 3) * 8;
  const int tok0 = rowTok[m0 + rA0];
  const int tok1 = rowTok[m0 + rA1];
  const unsigned short* srcA0 = xbf + (size_t)tok0 * DIM + sl;
  const unsigned short* srcA1 = xbf + (size_t)tok1 * DIM + sl;
  const size_t wb = (size_t)e * (size_t)(2 * DFFN) * DIM;
  const unsigned short* srcB0 = w13bf + wb + (size_t)(n0 + rA0) * DIM + sl;            // gate rows
  const unsigned short* srcB1 = w13bf + wb + (size_t)(DFFN + n0 + rA0) * DIM + sl;     // up rows

  char* dA0 = (char*)(&As[0][0]) + wv * 1024;
  char* dA1 = dA0 + 4096;
  char* dB0 = (char*)(&Bs[0][0]) + wv * 1024;
  char* dB1 = dB0 + 4096;

  const int lrow = ln & 15, lk = (ln >> 4) * 8;
  const bf16x8* pA[4]; const bf16x8* pB[4];
#pragma unroll
  for (int i = 0; i < 4; ++i) pA[i] = (const bf16x8*)&As[wr * 64 + i * 16 + lrow][lk];
#pragma unroll
  for (int j = 0; j < 4; ++j) {
    int br = (j < 2) ? (wc * 32 + j * 16 + lrow) : (64 + wc * 32 + (j - 2) * 16 + lrow);
    pB[j] = (const bf16x8*)&Bs[br][lk];
  }

  f32x4 acc[4][4] = {};
  for (int k0 = 0; k0 < DIM; k0 += 32) {
    gload16(srcA0 + k0, dA0);
    gload16(srcA1 + k0, dA1);
    gload16(srcB0 + k0, dB0);
    gload16(srcB1 + k0, dB1);
    __syncthreads();
    bf16x8 av[4], bv[4];
#pragma unroll
    for (int i = 0; i < 4; ++i) av[i] = *pA[i];
#pragma unroll
    for (int j = 0; j < 4; ++j) bv[j] = *pB[j];
#pragma unroll
    for (int i = 0; i < 4; ++i)
#pragma unroll
      for (int j = 0; j < 4; ++j)
        acc[i][j] = __builtin_amdgcn_mfma_f32_16x16x32_bf16(av[i], bv[j], acc[i][j], 0, 0, 0);
    __syncthreads();
  }

  // epilogue: h = silu(g) * u, store bf16.  C/D map: col=lane&15, row=(lane>>4)*4+reg
  const int rowb = m0 + wr * 64 + (ln >> 4) * 4;
#pragma unroll
  for (int i = 0; i < 4; ++i) {
#pragma unroll
    for (int j = 0; j < 2; ++j) {
      f32x4 g = acc[i][j], u = acc[i][j + 2];
      int f = n0 + wc * 32 + j * 16 + lrow;
#pragma unroll
      for (int r = 0; r < 4; ++r) {
        float gv = g[r];
        float hv = (gv / (1.f + __expf(-gv))) * u[r];
        H[(size_t)(rowb + i * 16 + r) * DFFN + f] = f2bf(hv);
      }
    }
  }
}

// ---------------- grouped GEMM2: out[tok] += wgt * (H @ w2[e]^T) ----------------
__global__ __launch_bounds__(256) void gemm2_kernel(
    const unsigned short* __restrict__ H, const unsigned short* __restrict__ w2bf,
    const int* __restrict__ rowTok, const float* __restrict__ rowWgt,
    const int* __restrict__ padOff, float* __restrict__ out) {
  __shared__ __align__(16) unsigned short As[BM][32];
  __shared__ __align__(16) unsigned short Bs[BM][32];

  const int m0 = blockIdx.y * BM;
  const int total = padOff[NEXP];
  if (m0 >= total) return;
  int e = 0;
#pragma unroll
  for (int i = 1; i < NEXP; ++i) if (m0 >= padOff[i]) e = i;
  const int n0 = blockIdx.x * 128;

  const int tid = threadIdx.x;
  const int wv = tid >> 6, ln = tid & 63;
  const int wr = wv >> 1, wc = wv & 1;

  const int rA0 = wv * 16 + (ln >> 2);
  const int rA1 = 64 + rA0;
  const int sl = (ln & 3) * 8;
  const unsigned short* srcA0 = H + (size_t)(m0 + rA0) * DFFN + sl;
  const unsigned short* srcA1 = H + (size_t)(m0 + rA1) * DFFN + sl;
  const size_t wb = (size_t)e * (size_t)DIM * DFFN;
  const unsigned short* srcB0 = w2bf + wb + (size_t)(n0 + rA0) * DFFN + sl;
  const unsigned short* srcB1 = w2bf + wb + (size_t)(n0 + rA1) * DFFN + sl;

  char* dA0 = (char*)(&As[0][0]) + wv * 1024;
  char* dA1 = dA0 + 4096;
  char* dB0 = (char*)(&Bs[0][0]) + wv * 1024;
  char* dB1 = dB0 + 4096;

  const int lrow = ln & 15, lk = (ln >> 4) * 8;
  const bf16x8* pA[4]; const bf16x8* pB[4];
#pragma unroll
  for (int i = 0; i < 4; ++i) pA[i] = (const bf16x8*)&As[wr * 64 + i * 16 + lrow][lk];
#pragma unroll
  for (int j = 0; j < 4; ++j) pB[j] = (const bf16x8*)&Bs[wc * 64 + j * 16 + lrow][lk];

  f32x4 acc[4][4] = {};
  for (int k0 = 0; k0 < DFFN; k0 += 32) {
    gload16(srcA0 + k0, dA0);
    gload16(srcA1 + k0, dA1);
    gload16(srcB0 + k0, dB0);
    gload16(srcB1 + k0, dB1);
    __syncthreads();
    bf16x8 av[4], bv[4];
#pragma unroll
    for (int i = 0; i < 4; ++i) av[i] = *pA[i];
#pragma unroll
    for (int j = 0; j < 4; ++j) bv[j] = *pB[j];
#pragma unroll
    for (int i = 0; i < 4; ++i)
#pragma unroll
      for (int j = 0; j < 4; ++j)
        acc[i][j] = __builtin_amdgcn_mfma_f32_16x16x32_bf16(av[i], bv[j], acc[i][j], 0, 0, 0);
    __syncthreads();
  }

  const int rowb = m0 + wr * 64 + (ln >> 4) * 4;
#pragma unroll
  for (int i = 0; i < 4; ++i) {
#pragma unroll
    for (int r = 0; r < 4; ++r) {
      int row = rowb + i * 16 + r;
      int tok = rowTok[row];
      float w = rowWgt[row];
      if (w != 0.f) {
        float* op = out + (size_t)tok * DIM + n0 + wc * 64 + lrow;
#pragma unroll
        for (int j = 0; j < 4; ++j) atomicAdd(op + j * 16, w * acc[i][j][r]);
      }
    }
  }
}

extern "C" void kernel_launch(void* const* d_in, const int* in_sizes, int n_in,
                              void* d_out, int out_size, void* d_ws, size_t ws_size,
                              hipStream_t stream) {
  const float* x      = (const float*)d_in[0];
  const float* gating = (const float*)d_in[1];
  const float* w13    = (const float*)d_in[2];
  const float* w2     = (const float*)d_in[3];
  float* out = (float*)d_out;

  char* ws = (char*)d_ws;
  size_t off = 0;
  auto alloc = [&](size_t bytes) { char* p = ws + off; off += (bytes + 255) & ~(size_t)255; return p; };
  int*   ctrl   = (int*)alloc(256);             // counts[8] | cursors[8] | padOff[9]
  int*   counts = ctrl;
  int*   cursors = ctrl + 8;
  int*   padOff = ctrl + 16;
  int*   sel    = (int*)alloc((size_t)2 * T_TOK * 4);
  float* selw   = (float*)alloc((size_t)2 * T_TOK * 4);
  int*   rowTok = (int*)alloc((size_t)MAXROWS * 4);
  float* rowWgt = (float*)alloc((size_t)MAXROWS * 4);
  unsigned short* xbf   = (unsigned short*)alloc((size_t)T_TOK * DIM * 2);
  unsigned short* w13bf = (unsigned short*)alloc((size_t)NEXP * 2 * DFFN * DIM * 2);
  unsigned short* w2bf  = (unsigned short*)alloc((size_t)NEXP * DIM * DFFN * 2);
  unsigned short* Hbuf  = (unsigned short*)alloc((size_t)MAXROWS * DFFN * 2);

  hipMemsetAsync(ctrl, 0, 64, stream);  // counts + cursors
  route_kernel<<<T_TOK / 256, 256, 0, stream>>>(gating, sel, selw, counts);
  offsets_kernel<<<1, 64, 0, stream>>>(counts, padOff);
  fill_kernel<<<MAXROWS / 256, 256, 0, stream>>>(rowTok, rowWgt);
  scatter_kernel<<<T_TOK / 256, 256, 0, stream>>>(sel, selw, padOff, cursors, rowTok, rowWgt);
  cvt_kernel<<<2048, 256, 0, stream>>>(x, xbf, T_TOK * DIM / 4);
  cvt_kernel<<<2048, 256, 0, stream>>>(w13, w13bf, NEXP * 2 * DFFN * DIM / 4);
  cvt_kernel<<<1024, 256, 0, stream>>>(w2, w2bf, NEXP * DIM * DFFN / 4);
  hipMemsetAsync(d_out, 0, (size_t)T_TOK * DIM * 4, stream);
  gemm1_kernel<<<dim3(2 * DFFN / 128, MAXROWS / BM), 256, 0, stream>>>(xbf, w13bf, rowTok, padOff, Hbuf);
  gemm2_kernel<<<dim3(DIM / 128, MAXROWS / BM), 256, 0, stream>>>(Hbuf, w2bf, rowTok, rowWgt, padOff, out);
}

// Round 2
// 1932.493 us; speedup vs baseline: 1.0349x; 1.0349x over previous
//
#include <hip/hip_runtime.h>
#include <stdint.h>

#define T_TOK 32768
#define DIM   1024
#define NEXP  8
#define DFFN  2048
#define MAXROWS 66560   // >= 65536 + 8*127 rounded to 128
#define BM 128

typedef __bf16 bf16x8 __attribute__((ext_vector_type(8)));
typedef float  f32x4  __attribute__((ext_vector_type(4)));
typedef unsigned short u16x8 __attribute__((ext_vector_type(8)));

__device__ __forceinline__ unsigned short f2bf(float f) {
  unsigned u = __float_as_uint(f);
  unsigned r = (u + 0x7fffu + ((u >> 16) & 1u)) >> 16;
  return (unsigned short)r;
}
__device__ __forceinline__ float bf2f(unsigned short u) {
  return __uint_as_float(((unsigned)u) << 16);
}

__device__ __forceinline__ void gload16(const void* g, void* l) {
  __builtin_amdgcn_global_load_lds(
      (__attribute__((address_space(1))) void*)(uintptr_t)g,
      (__attribute__((address_space(3))) void*)(uint32_t)(uintptr_t)l,
      16, 0, 0);
}

// XCD-aware bijective remap; nwg must be multiple of 8. Chunk = consecutive
// wgid range per XCD; interpret wgid n-major-slow so each XCD owns NX/8
// N-columns x all M (B-panel stays resident in its 4MiB L2).
__device__ __forceinline__ void xcd_remap(int NX, int NY, int& nb, int& mb) {
  int orig = blockIdx.y * NX + blockIdx.x;
  int q = (NX * NY) >> 3;
  int wgid = (orig & 7) * q + (orig >> 3);
  nb = wgid / NY;
  mb = wgid % NY;
}

// ---------------- routing ----------------
__global__ void route_kernel(const float* __restrict__ gating, int* __restrict__ sel,
                             float* __restrict__ selw, int* __restrict__ counts) {
  int t = blockIdx.x * 256 + threadIdx.x;
  if (t >= T_TOK) return;
  float4 a = ((const float4*)gating)[t * 2];
  float4 b = ((const float4*)gating)[t * 2 + 1];
  float l[8] = {a.x, a.y, a.z, a.w, b.x, b.y, b.z, b.w};
  int i0 = 0; float b0 = l[0];
#pragma unroll
  for (int i = 1; i < 8; ++i) if (l[i] > b0) { b0 = l[i]; i0 = i; }
  int i1 = -1; float b1 = -1e30f;
#pragma unroll
  for (int i = 0; i < 8; ++i) if (i != i0 && l[i] > b1) { b1 = l[i]; i1 = i; }
  float e1 = __expf(b1 - b0);
  float w0 = 1.f / (1.f + e1);
  float w1 = 1.f - w0;
  sel[2 * t] = i0;  sel[2 * t + 1] = i1;
  selw[2 * t] = w0; selw[2 * t + 1] = w1;
  atomicAdd(&counts[i0], 1);
  atomicAdd(&counts[i1], 1);
}

__global__ void offsets_kernel(const int* __restrict__ counts, int* __restrict__ padOff) {
  if (threadIdx.x == 0) {
    int off = 0;
    for (int e = 0; e < NEXP; ++e) { padOff[e] = off; off += (counts[e] + 127) & ~127; }
    padOff[NEXP] = off;
  }
}

__global__ void fill_kernel(int* __restrict__ rowTok, int* __restrict__ rowSlot) {
  int i = blockIdx.x * 256 + threadIdx.x;
  if (i < MAXROWS) { rowTok[i] = 0; rowSlot[i] = -1; }
}

__global__ void scatter_kernel(const int* __restrict__ sel, const int* __restrict__ padOff,
                               int* __restrict__ cursors,
                               int* __restrict__ rowTok, int* __restrict__ rowSlot) {
  int t = blockIdx.x * 256 + threadIdx.x;
  if (t >= T_TOK) return;
#pragma unroll
  for (int j = 0; j < 2; ++j) {
    int e = sel[2 * t + j];
    int pos = atomicAdd(&cursors[e], 1);
    int r = padOff[e] + pos;
    rowTok[r] = t;
    rowSlot[r] = 2 * t + j;
  }
}

// ---------------- f32 -> bf16 conversion ----------------
__global__ void cvt_kernel(const float* __restrict__ src, unsigned short* __restrict__ dst, int n4) {
  int i = blockIdx.x * blockDim.x + threadIdx.x;
  int stride = gridDim.x * blockDim.x;
  for (; i < n4; i += stride) {
    float4 v = ((const float4*)src)[i];
    ushort4 o;
    o.x = f2bf(v.x); o.y = f2bf(v.y); o.z = f2bf(v.z); o.w = f2bf(v.w);
    ((ushort4*)dst)[i] = o;
  }
}

// ---------------- grouped GEMM1: gu = x @ w13[e]^T, H = silu(g)*u ----------------
__global__ __launch_bounds__(256) void gemm1_kernel(
    const unsigned short* __restrict__ xbf, const unsigned short* __restrict__ w13bf,
    const int* __restrict__ rowTok, const int* __restrict__ padOff,
    unsigned short* __restrict__ H) {
  __shared__ __align__(16) unsigned short As[BM][32];
  __shared__ __align__(16) unsigned short Bs[BM][32];

  int nb, mb;
  xcd_remap(gridDim.x, gridDim.y, nb, mb);
  const int m0 = mb * BM;
  const int total = padOff[NEXP];
  if (m0 >= total) return;
  int e = 0;
#pragma unroll
  for (int i = 1; i < NEXP; ++i) if (m0 >= padOff[i]) e = i;
  const int n0 = nb * 64;  // f-column block

  const int tid = threadIdx.x;
  const int wv = tid >> 6, ln = tid & 63;
  const int wr = wv >> 1, wc = wv & 1;

  // XOR bank swizzle: LDS slot s holds global slot s^swz(row),
  // swz(row)=(row&3)^((row>>2)&3). Staging src offset and read offset both
  // reduce to the same per-lane constant:
  const int swz8 = (((ln & 3) ^ ((ln >> 2) & 3) ^ ((ln >> 4) & 3))) * 8;

  const int rA0 = wv * 16 + (ln >> 2);
  const int rA1 = 64 + rA0;
  const int tok0 = rowTok[m0 + rA0];
  const int tok1 = rowTok[m0 + rA1];
  const unsigned short* srcA0 = xbf + (size_t)tok0 * DIM + swz8;
  const unsigned short* srcA1 = xbf + (size_t)tok1 * DIM + swz8;
  const size_t wb = (size_t)e * (size_t)(2 * DFFN) * DIM;
  const unsigned short* srcB0 = w13bf + wb + (size_t)(n0 + rA0) * DIM + swz8;         // gate
  const unsigned short* srcB1 = w13bf + wb + (size_t)(DFFN + n0 + rA0) * DIM + swz8;  // up

  char* dA0 = (char*)(&As[0][0]) + wv * 1024;
  char* dA1 = dA0 + 4096;
  char* dB0 = (char*)(&Bs[0][0]) + wv * 1024;
  char* dB1 = dB0 + 4096;

  const int lrow = ln & 15;
  const bf16x8* pA[4]; const bf16x8* pB[4];
#pragma unroll
  for (int i = 0; i < 4; ++i) pA[i] = (const bf16x8*)&As[wr * 64 + i * 16 + lrow][swz8];
#pragma unroll
  for (int j = 0; j < 4; ++j) {
    int br = (j < 2) ? (wc * 32 + j * 16 + lrow) : (64 + wc * 32 + (j - 2) * 16 + lrow);
    pB[j] = (const bf16x8*)&Bs[br][swz8];
  }

  f32x4 acc[4][4] = {};
  for (int k0 = 0; k0 < DIM; k0 += 32) {
    gload16(srcA0 + k0, dA0);
    gload16(srcA1 + k0, dA1);
    gload16(srcB0 + k0, dB0);
    gload16(srcB1 + k0, dB1);
    __syncthreads();
    bf16x8 av[4], bv[4];
#pragma unroll
    for (int i = 0; i < 4; ++i) av[i] = *pA[i];
#pragma unroll
    for (int j = 0; j < 4; ++j) bv[j] = *pB[j];
#pragma unroll
    for (int i = 0; i < 4; ++i)
#pragma unroll
      for (int j = 0; j < 4; ++j)
        acc[i][j] = __builtin_amdgcn_mfma_f32_16x16x32_bf16(av[i], bv[j], acc[i][j], 0, 0, 0);
    __syncthreads();
  }

  // epilogue: h = silu(g) * u, store bf16.  C/D map: col=lane&15, row=(lane>>4)*4+reg
  const int rowb = m0 + wr * 64 + (ln >> 4) * 4;
#pragma unroll
  for (int i = 0; i < 4; ++i) {
#pragma unroll
    for (int j = 0; j < 2; ++j) {
      f32x4 g = acc[i][j], u = acc[i][j + 2];
      int f = n0 + wc * 32 + j * 16 + lrow;
#pragma unroll
      for (int r = 0; r < 4; ++r) {
        float gv = g[r];
        float hv = (gv / (1.f + __expf(-gv))) * u[r];
        H[(size_t)(rowb + i * 16 + r) * DFFN + f] = f2bf(hv);
      }
    }
  }
}

// ---------------- grouped GEMM2: Oslot[slot] = H @ w2[e]^T (unweighted, bf16) ---
__global__ __launch_bounds__(256) void gemm2_kernel(
    const unsigned short* __restrict__ H, const unsigned short* __restrict__ w2bf,
    const int* __restrict__ rowSlot, const int* __restrict__ padOff,
    unsigned short* __restrict__ Oslot) {
  __shared__ __align__(16) unsigned short As[BM][32];
  __shared__ __align__(16) unsigned short Bs[BM][32];

  int nb, mb;
  xcd_remap(gridDim.x, gridDim.y, nb, mb);
  const int m0 = mb * BM;
  const int total = padOff[NEXP];
  if (m0 >= total) return;
  int e = 0;
#pragma unroll
  for (int i = 1; i < NEXP; ++i) if (m0 >= padOff[i]) e = i;
  const int n0 = nb * 128;

  const int tid = threadIdx.x;
  const int wv = tid >> 6, ln = tid & 63;
  const int wr = wv >> 1, wc = wv & 1;

  const int swz8 = (((ln & 3) ^ ((ln >> 2) & 3) ^ ((ln >> 4) & 3))) * 8;

  const int rA0 = wv * 16 + (ln >> 2);
  const int rA1 = 64 + rA0;
  const unsigned short* srcA0 = H + (size_t)(m0 + rA0) * DFFN + swz8;
  const unsigned short* srcA1 = H + (size_t)(m0 + rA1) * DFFN + swz8;
  const size_t wb = (size_t)e * (size_t)DIM * DFFN;
  const unsigned short* srcB0 = w2bf + wb + (size_t)(n0 + rA0) * DFFN + swz8;
  const unsigned short* srcB1 = w2bf + wb + (size_t)(n0 + rA1) * DFFN + swz8;

  char* dA0 = (char*)(&As[0][0]) + wv * 1024;
  char* dA1 = dA0 + 4096;
  char* dB0 = (char*)(&Bs[0][0]) + wv * 1024;
  char* dB1 = dB0 + 4096;

  const int lrow = ln & 15;
  const bf16x8* pA[4]; const bf16x8* pB[4];
#pragma unroll
  for (int i = 0; i < 4; ++i) pA[i] = (const bf16x8*)&As[wr * 64 + i * 16 + lrow][swz8];
#pragma unroll
  for (int j = 0; j < 4; ++j) pB[j] = (const bf16x8*)&Bs[wc * 64 + j * 16 + lrow][swz8];

  f32x4 acc[4][4] = {};
  for (int k0 = 0; k0 < DFFN; k0 += 32) {
    gload16(srcA0 + k0, dA0);
    gload16(srcA1 + k0, dA1);
    gload16(srcB0 + k0, dB0);
    gload16(srcB1 + k0, dB1);
    __syncthreads();
    bf16x8 av[4], bv[4];
#pragma unroll
    for (int i = 0; i < 4; ++i) av[i] = *pA[i];
#pragma unroll
    for (int j = 0; j < 4; ++j) bv[j] = *pB[j];
#pragma unroll
    for (int i = 0; i < 4; ++i)
#pragma unroll
      for (int j = 0; j < 4; ++j)
        acc[i][j] = __builtin_amdgcn_mfma_f32_16x16x32_bf16(av[i], bv[j], acc[i][j], 0, 0, 0);
    __syncthreads();
  }

  const int rowb = m0 + wr * 64 + (ln >> 4) * 4;
#pragma unroll
  for (int i = 0; i < 4; ++i) {
#pragma unroll
    for (int r = 0; r < 4; ++r) {
      int row = rowb + i * 16 + r;
      int si = rowSlot[row];
      if (si >= 0) {
        unsigned short* op = Oslot + (size_t)si * DIM + n0 + wc * 64 + lrow;
#pragma unroll
        for (int j = 0; j < 4; ++j) op[j * 16] = f2bf(acc[i][j][r]);
      }
    }
  }
}

// ---------------- combine: out[t] = w0*Oslot[2t] + w1*Oslot[2t+1] ----------------
__global__ void combine_kernel(const unsigned short* __restrict__ Oslot,
                               const float* __restrict__ selw, float* __restrict__ out) {
  int idx = blockIdx.x * 256 + threadIdx.x;   // T_TOK*DIM/8 threads
  int t = idx >> 7;
  int c = (idx & 127) << 3;
  u16x8 a = *(const u16x8*)(Oslot + (size_t)(2 * t) * DIM + c);
  u16x8 b = *(const u16x8*)(Oslot + (size_t)(2 * t + 1) * DIM + c);
  float w0 = selw[2 * t], w1 = selw[2 * t + 1];
  float4 o0, o1;
  o0.x = w0 * bf2f(a[0]) + w1 * bf2f(b[0]);
  o0.y = w0 * bf2f(a[1]) + w1 * bf2f(b[1]);
  o0.z = w0 * bf2f(a[2]) + w1 * bf2f(b[2]);
  o0.w = w0 * bf2f(a[3]) + w1 * bf2f(b[3]);
  o1.x = w0 * bf2f(a[4]) + w1 * bf2f(b[4]);
  o1.y = w0 * bf2f(a[5]) + w1 * bf2f(b[5]);
  o1.z = w0 * bf2f(a[6]) + w1 * bf2f(b[6]);
  o1.w = w0 * bf2f(a[7]) + w1 * bf2f(b[7]);
  float4* op = (float4*)(out + (size_t)t * DIM + c);
  op[0] = o0; op[1] = o1;
}

extern "C" void kernel_launch(void* const* d_in, const int* in_sizes, int n_in,
                              void* d_out, int out_size, void* d_ws, size_t ws_size,
                              hipStream_t stream) {
  const float* x      = (const float*)d_in[0];
  const float* gating = (const float*)d_in[1];
  const float* w13    = (const float*)d_in[2];
  const float* w2     = (const float*)d_in[3];
  float* out = (float*)d_out;

  char* ws = (char*)d_ws;
  size_t off = 0;
  auto alloc = [&](size_t bytes) { char* p = ws + off; off += (bytes + 255) & ~(size_t)255; return p; };
  int*   ctrl    = (int*)alloc(256);            // counts[8] | cursors[8] | padOff[9]
  int*   counts  = ctrl;
  int*   cursors = ctrl + 8;
  int*   padOff  = ctrl + 16;
  int*   sel     = (int*)alloc((size_t)2 * T_TOK * 4);
  float* selw    = (float*)alloc((size_t)2 * T_TOK * 4);
  int*   rowTok  = (int*)alloc((size_t)MAXROWS * 4);
  int*   rowSlot = (int*)alloc((size_t)MAXROWS * 4);
  unsigned short* xbf   = (unsigned short*)alloc((size_t)T_TOK * DIM * 2);        // 64 MiB
  unsigned short* w13bf = (unsigned short*)alloc((size_t)NEXP * 2 * DFFN * DIM * 2); // 64 MiB
  unsigned short* w2bf  = (unsigned short*)alloc((size_t)NEXP * DIM * DFFN * 2);  // 32 MiB
  unsigned short* Hbuf  = (unsigned short*)alloc((size_t)MAXROWS * DFFN * 2);     // 260 MiB
  // Oslot [2*T_TOK][DIM] bf16 = exactly 128 MiB: alias over xbf+w13bf (dead after gemm1)
  unsigned short* Oslot = xbf;

  hipMemsetAsync(ctrl, 0, 64, stream);  // counts + cursors
  route_kernel<<<T_TOK / 256, 256, 0, stream>>>(gating, sel, selw, counts);
  offsets_kernel<<<1, 64, 0, stream>>>(counts, padOff);
  fill_kernel<<<MAXROWS / 256, 256, 0, stream>>>(rowTok, rowSlot);
  scatter_kernel<<<T_TOK / 256, 256, 0, stream>>>(sel, padOff, cursors, rowTok, rowSlot);
  cvt_kernel<<<2048, 256, 0, stream>>>(x, xbf, T_TOK * DIM / 4);
  cvt_kernel<<<2048, 256, 0, stream>>>(w13, w13bf, NEXP * 2 * DFFN * DIM / 4);
  cvt_kernel<<<1024, 256, 0, stream>>>(w2, w2bf, NEXP * DIM * DFFN / 4);
  gemm1_kernel<<<dim3(2 * DFFN / 128, MAXROWS / BM), 256, 0, stream>>>(xbf, w13bf, rowTok, padOff, Hbuf);
  gemm2_kernel<<<dim3(DIM / 128, MAXROWS / BM), 256, 0, stream>>>(Hbuf, w2bf, rowSlot, padOff, Oslot);
  combine_kernel<<<T_TOK * DIM / 8 / 256, 256, 0, stream>>>(Oslot, selw, out);
}